// Round 6
// baseline (169.470 us; speedup 1.0000x reference)
//
#include <hip/hip_runtime.h>
#include <cstdint>
#include <cstddef>

#define NG 3
#define NB 32
#define NT 1024
#define ND 512
#define NU 512

typedef __bf16 bf16x8 __attribute__((ext_vector_type(8)));
typedef float  f32x16 __attribute__((ext_vector_type(16)));

static __device__ __forceinline__ unsigned int f2bf(float f) {
    union { float f; unsigned int u; } v; v.f = f;
    return (v.u + 0x7FFFu + ((v.u >> 16) & 1u)) >> 16;   // RNE f32->bf16
}

// packed RNE f32x2 -> bf16x2 in one instruction
static __device__ __forceinline__ unsigned int cvt_pk_bf16(float lo, float hi) {
    unsigned int r;
    asm("v_cvt_pk_bf16_f32 %0, %1, %2" : "=v"(r) : "v"(lo), "v"(hi));
    return r;
}

static __device__ __forceinline__ bf16x8 ld_bf16x8(const char* base, int off) {
    return __builtin_bit_cast(bf16x8, *(const uint4*)(base + off));
}

#define AS1(p) ((const __attribute__((address_space(1))) void*)(p))
#define AS3(p) ((__attribute__((address_space(3))) void*)(p))

// ---------- kernel 1: qb[g,b,u] = sum_d query[g,b,d]*W1[g,d,u] + b1 + b2 ----------
__global__ __launch_bounds__(256) void prep_qb_kernel(
    const float* __restrict__ query, const float* __restrict__ W1,
    const float* __restrict__ b1, const float* __restrict__ b2,
    float* __restrict__ qb)
{
    __shared__ float qs[NB][ND];                    // 64 KiB
    const int g  = blockIdx.x >> 3;
    const int uc = blockIdx.x & 7;
    const int tid = threadIdx.x;

    const float4* qsrc = (const float4*)(query + (size_t)g * NB * ND);
    #pragma unroll
    for (int i = 0; i < 16; ++i)
        ((float4*)&qs[0][0])[tid + i * 256] = qsrc[tid + i * 256];
    __syncthreads();

    const int u  = uc * 64 + (tid & 63);
    const int b0 = tid >> 6;                        // 0..3
    float acc[8] = {};
    const float* w1col = W1 + (size_t)g * ND * NU + u;
    for (int d = 0; d < ND; ++d) {
        float w = w1col[(size_t)d * NU];            // coalesced over u
        #pragma unroll
        for (int j = 0; j < 8; ++j)
            acc[j] = fmaf(qs[b0 + 4 * j][d], w, acc[j]);  // LDS broadcast
    }
    const float bias = b1[g * NU + u] + b2[g * NU + u];
    #pragma unroll
    for (int j = 0; j < 8; ++j)
        qb[((size_t)g * NB + (b0 + 4 * j)) * NU + u] = acc[j] + bias;
}

// ---------- kernel 2: w2t = swizzled bf16 image of W2^T ----------
// Per g: 16 u-chunks (32 u) x 4 k-quarters (128 k) of 8 KiB each.
// Within an 8 KiB block: row r = u&31 (256 B), byte = (k'<<1) ^ ((r&7)<<4),
// k' = k&127. Linear-DMA-ready for per-wave private staging.
__global__ __launch_bounds__(256) void prep_w2t_kernel(
    const float* __restrict__ W2, char* __restrict__ w2t)
{
    __shared__ float tile[64][65];                  // +1 pad: conflict-free transpose
    const int g  = blockIdx.x >> 6;
    const int tb = blockIdx.x & 63;
    const int d0 = (tb >> 3) * 64;
    const int u0 = (tb & 7) * 64;
    const int tx = threadIdx.x & 63;
    const int ty = threadIdx.x >> 6;

    const float* src = W2 + (size_t)g * ND * NU;
    #pragma unroll
    for (int k = 0; k < 16; ++k) {
        int r = ty + 4 * k;
        tile[r][tx] = src[(size_t)(d0 + r) * NU + (u0 + tx)];   // tile[d_loc][u_loc]
    }
    __syncthreads();
    char* dstg = w2t + (size_t)g * 16 * 32768;
    #pragma unroll
    for (int k = 0; k < 16; ++k) {
        int ul = ty + 4 * k;
        int u  = u0 + ul;
        int d  = d0 + tx;
        unsigned short h = (unsigned short)f2bf(tile[tx][ul]);
        int r  = u & 31;
        int kq = d >> 7;
        int kp = d & 127;
        size_t off = (size_t)(u >> 5) * 32768 + (size_t)kq * 8192
                   + (size_t)(r << 8)
                   + (size_t)(((kp << 1) ^ ((r & 7) << 4)));
        *(unsigned short*)(dstg + off) = h;
    }
}

// ---------- kernel 3: fused score = V . tanh(qb + values@W2) + bV ----------
// BARRIER-FREE main loop: each wave is fully self-paced. Wave owns 32 t-rows;
// A (values) in 128 regs as bf16 fragments (all indices compile-time).
// B streamed through a PER-WAVE private 2 x 8 KiB LDS double buffer,
// 8 KiB = one (u-chunk, k-quarter); staged 1 phase ahead via global_load_lds,
// counted vmcnt(8). No s_barrier in the loop -> zero inter-wave coupling.
__global__ __launch_bounds__(256, 2) void score_kernel(
    const float* __restrict__ values, const char* __restrict__ w2t,
    const float* __restrict__ qb, const float* __restrict__ Vvec,
    const float* __restrict__ bV, float* __restrict__ scores)
{
    __shared__ char  Bs[4][2][8192];                // 64 KiB: per-wave dbuf
    __shared__ float qbs[NU];
    __shared__ float Vs[NU];

    const int blk = blockIdx.x;
    const int g   = blk >> 8;                       // 256 blocks per g
    const int rem = blk & 255;
    const int b   = rem >> 3;
    const int t0  = (rem & 7) << 7;                 // 8 tiles of 128 rows
    const int tid  = threadIdx.x;
    const int lane = tid & 63;
    const int wave = tid >> 6;

    const char* w2g = w2t + ((size_t)g << 19);      // g * 512 KiB

    // stage 8 KiB block (u-chunk nuc, k-quarter nkq) into dst: 8 x 16B per lane
    auto stage = [&](int nuc, int nkq, char* dst) {
        const char* src = w2g + ((size_t)nuc << 15) + (nkq << 13) + (lane << 4);
        char* d = dst + (lane << 4);
        #pragma unroll
        for (int i = 0; i < 8; ++i)
            __builtin_amdgcn_global_load_lds(AS1(src + (i << 10)),
                                             AS3(d + (i << 10)), 16, 0, 0);
    };

    // ---- A tile -> registers (bf16 MFMA fragments), static indices ----
    bf16x8 afrag[32];
    {
        const int arow_t = t0 + (wave << 5) + (lane & 31);
        const float* arow = values + (((size_t)g * NB + b) * NT + arow_t) * ND;
        const int acol = (lane >> 5) << 3;          // k-half of fragment: 0 or 8
        #pragma unroll
        for (int kk = 0; kk < 32; ++kk) {
            const float4* ap = (const float4*)(arow + (kk << 4) + acol);
            float4 v0 = ap[0], v1 = ap[1];
            union { bf16x8 v; unsigned int u[4]; } t;
            t.u[0] = cvt_pk_bf16(v0.x, v0.y);
            t.u[1] = cvt_pk_bf16(v0.z, v0.w);
            t.u[2] = cvt_pk_bf16(v1.x, v1.y);
            t.u[3] = cvt_pk_bf16(v1.z, v1.w);
            afrag[kk] = t.v;
        }
    }

    {   // qb(+biases) and V via LDS-DMA (block-cooperative)
        const float* qsrc = qb + ((size_t)g * NB + b) * NU;
        const float* vsrc = Vvec + (size_t)g * NU;
        __builtin_amdgcn_global_load_lds(AS1(qsrc + tid),       AS3(&qbs[tid]),       4, 0, 0);
        __builtin_amdgcn_global_load_lds(AS1(qsrc + tid + 256), AS3(&qbs[tid + 256]), 4, 0, 0);
        __builtin_amdgcn_global_load_lds(AS1(vsrc + tid),       AS3(&Vs[tid]),        4, 0, 0);
        __builtin_amdgcn_global_load_lds(AS1(vsrc + tid + 256), AS3(&Vs[tid + 256]),  4, 0, 0);
    }

    char* myB0 = &Bs[wave][0][0];
    char* myB1 = &Bs[wave][1][0];
    stage(0, 0, myB0);                              // phase 0 data

    // full drain + one barrier: qbs/Vs visible to all waves, FIFO state clean
    asm volatile("s_waitcnt vmcnt(0) lgkmcnt(0)" ::: "memory");
    __builtin_amdgcn_s_barrier();

    const int brow  = lane & 31;
    const int h16   = (lane >> 5) << 4;             // 0 or 16
    const int bswz  = (brow & 7) << 4;
    const int bbase = brow << 8;                    // 256-B rows

    float p[16] = {};                               // per-lane score partials

    // one k-quarter phase: stage next, counted wait, 8 ds_read + 8 MFMA
    #define PHASE(RB, AFBASE, NUC, NKQ, SB)                                      \
        stage((NUC), (NKQ), (SB));                                               \
        asm volatile("s_waitcnt vmcnt(8)" ::: "memory");                         \
        __builtin_amdgcn_sched_barrier(0);                                       \
        __builtin_amdgcn_s_setprio(1);                                           \
        _Pragma("unroll")                                                        \
        for (int j = 0; j < 8; ++j) {                                            \
            bf16x8 bb = ld_bf16x8((RB), bbase + ((((j) << 5) + h16) ^ bswz));    \
            acc = __builtin_amdgcn_mfma_f32_32x32x16_bf16(afrag[(AFBASE) + j],   \
                                                          bb, acc, 0, 0, 0);     \
        }                                                                        \
        __builtin_amdgcn_s_setprio(0);

    #pragma unroll 1
    for (int uc = 0; uc < 16; ++uc) {
        f32x16 acc = (f32x16)(0.0f);
        PHASE(myB0,  0, uc, 1, myB1)                // kq0: read B0, stage (uc,1)
        PHASE(myB1,  8, uc, 2, myB0)                // kq1: read B1, stage (uc,2)
        PHASE(myB0, 16, uc, 3, myB1)                // kq2: read B0, stage (uc,3)
        PHASE(myB1, 24, (uc + 1) & 15, 0, myB0)     // kq3: read B1, stage next uc
        // epilogue: tanh + V-dot for u-chunk uc
        {
            const int u = (uc << 5) + brow;
            const float qv = qbs[u], vv = Vs[u];
            #pragma unroll
            for (int r = 0; r < 16; ++r) {
                // tanh(x) = 1 - 2/(exp2(2*log2e*x)+1)
                float x  = acc[r] + qv;
                float e  = exp2f(2.8853900817779268f * x);
                float th = 1.0f - 2.0f * __builtin_amdgcn_rcpf(e + 1.0f);
                p[r] = fmaf(th, vv, p[r]);
            }
        }
    }
    #undef PHASE

    asm volatile("s_waitcnt vmcnt(0)" ::: "memory");   // retire stray tail DMA

    // reduce over u-columns (each 32-lane half sums its 32 cols)
    #pragma unroll
    for (int r = 0; r < 16; ++r) {
        float v = p[r];
        v += __shfl_xor(v, 1);
        v += __shfl_xor(v, 2);
        v += __shfl_xor(v, 4);
        v += __shfl_xor(v, 8);
        v += __shfl_xor(v, 16);
        p[r] = v;
    }
    if ((lane & 31) == 0) {
        const float bv = bV[g];
        float* srow = scores + ((size_t)g * NB + b) * NT + t0 + (wave << 5);
        #pragma unroll
        for (int r = 0; r < 16; ++r) {
            int t_local = (r & 3) + 8 * (r >> 2) + 4 * (lane >> 5);   // 32x32 C/D row map
            srow[t_local] = p[r] + bv;
        }
    }
}

// ---------- kernel 4: softmax over T + context, 4 d-slices per (g,b) ----------
__global__ __launch_bounds__(256) void finish_kernel(
    const float* __restrict__ scores, const float* __restrict__ values,
    float* __restrict__ out_ctx, float* __restrict__ out_w)
{
    __shared__ float sl[NT];
    __shared__ float red[16];
    __shared__ float cred[4][128];
    const int blk   = blockIdx.x;
    const int gb    = blk >> 2;                     // 0..95
    const int slice = blk & 3;                      // d-slice of 128
    const int tid = threadIdx.x;
    const int lane = tid & 63, wid = tid >> 6;

    const float* srow = scores + (size_t)gb * NT;
    float s[4];
    #pragma unroll
    for (int j = 0; j < 4; ++j) s[j] = srow[tid + 256 * j];

    float m = fmaxf(fmaxf(s[0], s[1]), fmaxf(s[2], s[3]));
    #pragma unroll
    for (int mask = 32; mask; mask >>= 1) m = fmaxf(m, __shfl_xor(m, mask));
    if (lane == 0) red[wid] = m;
    __syncthreads();
    const float gm = fmaxf(fmaxf(red[0], red[1]), fmaxf(red[2], red[3]));

    float e[4], ps = 0.f;
    #pragma unroll
    for (int j = 0; j < 4; ++j) { e[j] = __expf(s[j] - gm); ps += e[j]; }
    #pragma unroll
    for (int mask = 32; mask; mask >>= 1) ps += __shfl_xor(ps, mask);
    if (lane == 0) red[8 + wid] = ps;
    __syncthreads();
    const float inv = 1.f / (red[8] + red[9] + red[10] + red[11]);

    #pragma unroll
    for (int j = 0; j < 4; ++j) {
        float w = e[j] * inv;
        sl[tid + 256 * j] = w;
        if (slice == 0) out_w[(size_t)gb * NT + tid + 256 * j] = w;
    }
    __syncthreads();

    // context for this 128-d slice: 64 d-pairs x 4 t-interleaved groups
    const int dp = tid & 63;
    const int tg = tid >> 6;
    const float* vbase = values + (size_t)gb * NT * ND + slice * 128 + dp * 2;
    float ax = 0.f, ay = 0.f;
    #pragma unroll 4
    for (int t = tg; t < NT; t += 4) {
        float2 v = *(const float2*)(vbase + (size_t)t * ND);
        float w = sl[t];                            // broadcast within tg group
        ax = fmaf(w, v.x, ax);
        ay = fmaf(w, v.y, ay);
    }
    cred[tg][dp * 2]     = ax;
    cred[tg][dp * 2 + 1] = ay;
    __syncthreads();
    if (tid < 128) {
        float r = cred[0][tid] + cred[1][tid] + cred[2][tid] + cred[3][tid];
        out_ctx[(size_t)gb * ND + slice * 128 + tid] = r;
    }
}

extern "C" void kernel_launch(void* const* d_in, const int* in_sizes, int n_in,
                              void* d_out, int out_size, void* d_ws, size_t ws_size,
                              hipStream_t stream)
{
    (void)in_sizes; (void)n_in; (void)out_size; (void)ws_size;
    const float* query  = (const float*)d_in[0];
    const float* values = (const float*)d_in[1];
    const float* W1     = (const float*)d_in[2];
    const float* b1     = (const float*)d_in[3];
    const float* W2     = (const float*)d_in[4];
    const float* b2     = (const float*)d_in[5];
    const float* Vv     = (const float*)d_in[6];
    const float* bV     = (const float*)d_in[7];

    float* out_ctx = (float*)d_out;
    float* out_w   = out_ctx + (size_t)NG * NB * ND;

    // ws: qb (192 KiB) | scores (384 KiB) | w2t swizzled bf16 image (1.5 MiB)
    float* qb     = (float*)d_ws;
    float* scores = qb + (size_t)NG * NB * NU;
    char*  w2t    = (char*)(scores + (size_t)NG * NB * NT);

    prep_qb_kernel <<<NG * 8,             256, 0, stream>>>(query, W1, b1, b2, qb);
    prep_w2t_kernel<<<NG * 64,            256, 0, stream>>>(W2, w2t);
    score_kernel   <<<NG * NB * (NT/128), 256, 0, stream>>>(values, w2t, qb, Vv, bV, scores);
    finish_kernel  <<<NG * NB * 4,        256, 0, stream>>>(scores, values, out_ctx, out_w);
}

// Round 7
// 148.432 us; speedup vs baseline: 1.1417x; 1.1417x over previous
//
#include <hip/hip_runtime.h>
#include <cstdint>
#include <cstddef>

#define NG 3
#define NB 32
#define NT 1024
#define ND 512
#define NU 512

typedef __bf16 bf16x8 __attribute__((ext_vector_type(8)));
typedef float  f32x16 __attribute__((ext_vector_type(16)));

static __device__ __forceinline__ unsigned int f2bf(float f) {
    union { float f; unsigned int u; } v; v.f = f;
    return (v.u + 0x7FFFu + ((v.u >> 16) & 1u)) >> 16;   // RNE f32->bf16
}

// packed RNE f32x2 -> bf16x2 in one instruction
static __device__ __forceinline__ unsigned int cvt_pk_bf16(float lo, float hi) {
    unsigned int r;
    asm("v_cvt_pk_bf16_f32 %0, %1, %2" : "=v"(r) : "v"(lo), "v"(hi));
    return r;
}

static __device__ __forceinline__ bf16x8 ld_bf16x8(const char* base, int off) {
    return __builtin_bit_cast(bf16x8, *(const uint4*)(base + off));
}

#define AS1(p) ((const __attribute__((address_space(1))) void*)(p))
#define AS3(p) ((__attribute__((address_space(3))) void*)(p))

// ---------- kernel 1: qb[g,b,u] = sum_d query[g,b,d]*W1[g,d,u] + b1 + b2 ----------
__global__ __launch_bounds__(256) void prep_qb_kernel(
    const float* __restrict__ query, const float* __restrict__ W1,
    const float* __restrict__ b1, const float* __restrict__ b2,
    float* __restrict__ qb)
{
    __shared__ float qs[NB][ND];                    // 64 KiB
    const int g  = blockIdx.x >> 3;
    const int uc = blockIdx.x & 7;
    const int tid = threadIdx.x;

    const float4* qsrc = (const float4*)(query + (size_t)g * NB * ND);
    #pragma unroll
    for (int i = 0; i < 16; ++i)
        ((float4*)&qs[0][0])[tid + i * 256] = qsrc[tid + i * 256];
    __syncthreads();

    const int u  = uc * 64 + (tid & 63);
    const int b0 = tid >> 6;                        // 0..3
    float acc[8] = {};
    const float* w1col = W1 + (size_t)g * ND * NU + u;
    for (int d = 0; d < ND; ++d) {
        float w = w1col[(size_t)d * NU];            // coalesced over u
        #pragma unroll
        for (int j = 0; j < 8; ++j)
            acc[j] = fmaf(qs[b0 + 4 * j][d], w, acc[j]);  // LDS broadcast
    }
    const float bias = b1[g * NU + u] + b2[g * NU + u];
    #pragma unroll
    for (int j = 0; j < 8; ++j)
        qb[((size_t)g * NB + (b0 + 4 * j)) * NU + u] = acc[j] + bias;
}

// ---------- kernel 2: w2t = swizzled bf16 image of W2^T ----------
// Per g: 16 chunks (u-groups of 32) of 32 KiB. Within a chunk,
// byte(r,d) = r*1024 + ((d*2) ^ ((r&7)<<4)), r = u&31. Linear-DMA-ready.
__global__ __launch_bounds__(256) void prep_w2t_kernel(
    const float* __restrict__ W2, char* __restrict__ w2t)
{
    __shared__ float tile[64][65];                  // +1 pad: conflict-free transpose
    const int g  = blockIdx.x >> 6;
    const int tb = blockIdx.x & 63;
    const int d0 = (tb >> 3) * 64;
    const int u0 = (tb & 7) * 64;
    const int tx = threadIdx.x & 63;
    const int ty = threadIdx.x >> 6;

    const float* src = W2 + (size_t)g * ND * NU;
    #pragma unroll
    for (int k = 0; k < 16; ++k) {
        int r = ty + 4 * k;
        tile[r][tx] = src[(size_t)(d0 + r) * NU + (u0 + tx)];   // tile[d_loc][u_loc]
    }
    __syncthreads();
    char* dstg = w2t + (size_t)g * 16 * 32768;
    #pragma unroll
    for (int k = 0; k < 16; ++k) {
        int ul = ty + 4 * k;
        int u  = u0 + ul;
        int d  = d0 + tx;
        unsigned short h = (unsigned short)f2bf(tile[tx][ul]);
        int r = u & 31;
        size_t off = (size_t)(u >> 5) * 32768
                   + (size_t)(((r << 10) | (d << 1)) ^ ((r & 7) << 4));
        *(unsigned short*)(dstg + off) = h;
    }
}

// ---------- kernel 3: fused score = V . tanh(qb + values@W2) + bV ----------
// Round-5 ring-3 structure + FORCED A-panel register residency.
// 4 waves; wave owns 32 t-rows; A (values) in 128 regs as bf16 fragments,
// static indices AND keep-alive pins after the loop so the allocator cannot
// rematerialize the loads inside the loop (the round-2..6 hidden stall).
__global__ __launch_bounds__(256, 2) void score_kernel(
    const float* __restrict__ values, const char* __restrict__ w2t,
    const float* __restrict__ qb, const float* __restrict__ Vvec,
    const float* __restrict__ bV, float* __restrict__ scores)
{
    __shared__ char  Bs[3][16384];                  // 48 KiB ring
    __shared__ float qbs[NU];
    __shared__ float Vs[NU];

    const int blk = blockIdx.x;
    const int g   = blk >> 8;                       // 256 blocks per g
    const int rem = blk & 255;
    const int b   = rem >> 3;
    const int t0  = (rem & 7) << 7;                 // 8 tiles of 128 rows
    const int tid  = threadIdx.x;
    const int lane = tid & 63;
    const int wave = tid >> 6;

    const char* w2g = w2t + ((size_t)g << 19);      // g * 512 KiB

    // stage half-chunk ph into buf: 16 KiB, 4 x 16B loads per thread
    auto stage = [&](int ph, char* buf) {
        const char* src = w2g + ((size_t)(ph >> 1) << 15) + ((ph & 1) << 9)
                        + (wave << 13) + ((lane >> 5) << 10) + ((lane & 31) << 4);
        char* dst = buf + (wave << 12) + (lane << 4);
        #pragma unroll
        for (int i = 0; i < 4; ++i)
            __builtin_amdgcn_global_load_lds(AS1(src + (i << 11)),
                                             AS3(dst + (i << 10)), 16, 0, 0);
    };

    {   // qb(+biases) and V via LDS-DMA
        const float* qsrc = qb + ((size_t)g * NB + b) * NU;
        const float* vsrc = Vvec + (size_t)g * NU;
        __builtin_amdgcn_global_load_lds(AS1(qsrc + tid),       AS3(&qbs[tid]),       4, 0, 0);
        __builtin_amdgcn_global_load_lds(AS1(qsrc + tid + 256), AS3(&qbs[tid + 256]), 4, 0, 0);
        __builtin_amdgcn_global_load_lds(AS1(vsrc + tid),       AS3(&Vs[tid]),        4, 0, 0);
        __builtin_amdgcn_global_load_lds(AS1(vsrc + tid + 256), AS3(&Vs[tid + 256]),  4, 0, 0);
    }
    stage(0, Bs[0]);
    stage(1, Bs[1]);

    // ---- A tile -> registers (bf16 MFMA fragments), static indices ----
    bf16x8 afrag[32];
    {
        const int arow_t = t0 + (wave << 5) + (lane & 31);
        const float* arow = values + (((size_t)g * NB + b) * NT + arow_t) * ND;
        const int acol = (lane >> 5) << 3;          // k-half of fragment: 0 or 8
        #pragma unroll
        for (int kk = 0; kk < 32; ++kk) {
            const float4* ap = (const float4*)(arow + (kk << 4) + acol);
            float4 v0 = ap[0], v1 = ap[1];
            union { bf16x8 v; unsigned int u[4]; } t;
            t.u[0] = cvt_pk_bf16(v0.x, v0.y);
            t.u[1] = cvt_pk_bf16(v0.z, v0.w);
            t.u[2] = cvt_pk_bf16(v1.x, v1.y);
            t.u[3] = cvt_pk_bf16(v1.z, v1.w);
            afrag[kk] = t.v;
        }
    }

    asm volatile("s_waitcnt vmcnt(0) lgkmcnt(0)" ::: "memory");
    __builtin_amdgcn_s_barrier();

    const int brow  = lane & 31;
    const int bswz  = (brow & 7) << 4;
    const int bbase = (brow << 9) + ((lane >> 5) << 4);

    float p[16] = {};                               // per-lane score partials

    char* bA = (char*)Bs[0];                        // even-phase read buffer
    char* bB = (char*)Bs[1];                        // odd-phase read buffer
    char* bC = (char*)Bs[2];                        // even-phase stage target

    #pragma unroll 1
    for (int uc = 0; uc < 16; ++uc) {
        const int ph0 = uc << 1;
        f32x16 acc0 = (f32x16)(0.0f);
        f32x16 acc1 = (f32x16)(0.0f);

        // ===== even phase: reads bA (k 0..255), stages ph0+2 into bC =====
        if (uc < 15) stage(ph0 + 2, bC);
        __builtin_amdgcn_s_setprio(1);
        #pragma unroll
        for (int kk = 0; kk < 16; kk += 2) {
            bf16x8 b0 = ld_bf16x8(bA, (bbase + (kk << 5)) ^ bswz);
            bf16x8 b1 = ld_bf16x8(bA, (bbase + ((kk + 1) << 5)) ^ bswz);
            acc0 = __builtin_amdgcn_mfma_f32_32x32x16_bf16(afrag[kk],     b0, acc0, 0, 0, 0);
            acc1 = __builtin_amdgcn_mfma_f32_32x32x16_bf16(afrag[kk + 1], b1, acc1, 0, 0, 0);
        }
        __builtin_amdgcn_s_setprio(0);
        if (uc < 15) {
            asm volatile("s_waitcnt vmcnt(4)" ::: "memory");   // ph0+1 landed; ph0+2 in flight
        } else {
            asm volatile("s_waitcnt vmcnt(0)" ::: "memory");   // tail: ph 31 landed
        }
        __builtin_amdgcn_s_barrier();

        // ===== odd phase: reads bB (k 256..511), stages ph0+3 into old bA =====
        if (uc < 15) stage(ph0 + 3, bA);
        __builtin_amdgcn_s_setprio(1);
        #pragma unroll
        for (int kk = 0; kk < 16; kk += 2) {
            bf16x8 b0 = ld_bf16x8(bB, (bbase + (kk << 5)) ^ bswz);
            bf16x8 b1 = ld_bf16x8(bB, (bbase + ((kk + 1) << 5)) ^ bswz);
            acc0 = __builtin_amdgcn_mfma_f32_32x32x16_bf16(afrag[16 + kk],     b0, acc0, 0, 0, 0);
            acc1 = __builtin_amdgcn_mfma_f32_32x32x16_bf16(afrag[16 + kk + 1], b1, acc1, 0, 0, 0);
        }
        __builtin_amdgcn_s_setprio(0);

        // epilogue: tanh + V-dot for u-chunk uc
        {
            const int u = (uc << 5) + brow;
            const float qv = qbs[u], vv = Vs[u];
            #pragma unroll
            for (int r = 0; r < 16; ++r) {
                // tanh(x) = 1 - 2/(exp2(2*log2e*x)+1)
                float x  = (acc0[r] + acc1[r]) + qv;
                float e  = exp2f(2.8853900817779268f * x);
                float th = 1.0f - 2.0f * __builtin_amdgcn_rcpf(e + 1.0f);
                p[r] = fmaf(th, vv, p[r]);
            }
        }

        if (uc < 15) {
            asm volatile("s_waitcnt vmcnt(4)" ::: "memory");   // ph0+2 landed; ph0+3 in flight
            __builtin_amdgcn_s_barrier();
        }

        // rotate ring: (A,B,C) <- (C,A,B)
        char* t = bA; bA = bC; bC = bB; bB = t;
    }

    // ---- keep-alive pins: force afrag to stay register-resident across the
    //      whole main loop (defeats load+cvt rematerialization/sinking) ----
    #pragma unroll
    for (int kk = 0; kk < 32; ++kk)
        asm volatile("" :: "v"(afrag[kk]));

    // reduce over u-columns (each 32-lane half sums its 32 cols)
    #pragma unroll
    for (int r = 0; r < 16; ++r) {
        float v = p[r];
        v += __shfl_xor(v, 1);
        v += __shfl_xor(v, 2);
        v += __shfl_xor(v, 4);
        v += __shfl_xor(v, 8);
        v += __shfl_xor(v, 16);
        p[r] = v;
    }
    if ((lane & 31) == 0) {
        const float bv = bV[g];
        float* srow = scores + ((size_t)g * NB + b) * NT + t0 + (wave << 5);
        #pragma unroll
        for (int r = 0; r < 16; ++r) {
            int t_local = (r & 3) + 8 * (r >> 2) + 4 * (lane >> 5);   // 32x32 C/D row map
            srow[t_local] = p[r] + bv;
        }
    }
}

// ---------- kernel 4: softmax over T + context, 4 d-slices per (g,b) ----------
__global__ __launch_bounds__(256) void finish_kernel(
    const float* __restrict__ scores, const float* __restrict__ values,
    float* __restrict__ out_ctx, float* __restrict__ out_w)
{
    __shared__ float sl[NT];
    __shared__ float red[16];
    __shared__ float cred[4][128];
    const int blk   = blockIdx.x;
    const int gb    = blk >> 2;                     // 0..95
    const int slice = blk & 3;                      // d-slice of 128
    const int tid = threadIdx.x;
    const int lane = tid & 63, wid = tid >> 6;

    const float* srow = scores + (size_t)gb * NT;
    float s[4];
    #pragma unroll
    for (int j = 0; j < 4; ++j) s[j] = srow[tid + 256 * j];

    float m = fmaxf(fmaxf(s[0], s[1]), fmaxf(s[2], s[3]));
    #pragma unroll
    for (int mask = 32; mask; mask >>= 1) m = fmaxf(m, __shfl_xor(m, mask));
    if (lane == 0) red[wid] = m;
    __syncthreads();
    const float gm = fmaxf(fmaxf(red[0], red[1]), fmaxf(red[2], red[3]));

    float e[4], ps = 0.f;
    #pragma unroll
    for (int j = 0; j < 4; ++j) { e[j] = __expf(s[j] - gm); ps += e[j]; }
    #pragma unroll
    for (int mask = 32; mask; mask >>= 1) ps += __shfl_xor(ps, mask);
    if (lane == 0) red[8 + wid] = ps;
    __syncthreads();
    const float inv = 1.f / (red[8] + red[9] + red[10] + red[11]);

    #pragma unroll
    for (int j = 0; j < 4; ++j) {
        float w = e[j] * inv;
        sl[tid + 256 * j] = w;
        if (slice == 0) out_w[(size_t)gb * NT + tid + 256 * j] = w;
    }
    __syncthreads();

    // context for this 128-d slice: 64 d-pairs x 4 t-interleaved groups
    const int dp = tid & 63;
    const int tg = tid >> 6;
    const float* vbase = values + (size_t)gb * NT * ND + slice * 128 + dp * 2;
    float ax = 0.f, ay = 0.f;
    #pragma unroll 4
    for (int t = tg; t < NT; t += 4) {
        float2 v = *(const float2*)(vbase + (size_t)t * ND);
        float w = sl[t];                            // broadcast within tg group
        ax = fmaf(w, v.x, ax);
        ay = fmaf(w, v.y, ay);
    }
    cred[tg][dp * 2]     = ax;
    cred[tg][dp * 2 + 1] = ay;
    __syncthreads();
    if (tid < 128) {
        float r = cred[0][tid] + cred[1][tid] + cred[2][tid] + cred[3][tid];
        out_ctx[(size_t)gb * ND + slice * 128 + tid] = r;
    }
}

extern "C" void kernel_launch(void* const* d_in, const int* in_sizes, int n_in,
                              void* d_out, int out_size, void* d_ws, size_t ws_size,
                              hipStream_t stream)
{
    (void)in_sizes; (void)n_in; (void)out_size; (void)ws_size;
    const float* query  = (const float*)d_in[0];
    const float* values = (const float*)d_in[1];
    const float* W1     = (const float*)d_in[2];
    const float* b1     = (const float*)d_in[3];
    const float* W2     = (const float*)d_in[4];
    const float* b2     = (const float*)d_in[5];
    const float* Vv     = (const float*)d_in[6];
    const float* bV     = (const float*)d_in[7];

    float* out_ctx = (float*)d_out;
    float* out_w   = out_ctx + (size_t)NG * NB * ND;

    // ws: qb (192 KiB) | scores (384 KiB) | w2t swizzled bf16 image (1.5 MiB)
    float* qb     = (float*)d_ws;
    float* scores = qb + (size_t)NG * NB * NU;
    char*  w2t    = (char*)(scores + (size_t)NG * NB * NT);

    prep_qb_kernel <<<NG * 8,             256, 0, stream>>>(query, W1, b1, b2, qb);
    prep_w2t_kernel<<<NG * 64,            256, 0, stream>>>(W2, w2t);
    score_kernel   <<<NG * NB * (NT/128), 256, 0, stream>>>(values, w2t, qb, Vv, bV, scores);
    finish_kernel  <<<NG * NB * 4,        256, 0, stream>>>(scores, values, out_ctx, out_w);
}

// Round 8
// 147.943 us; speedup vs baseline: 1.1455x; 1.0033x over previous
//
#include <hip/hip_runtime.h>
#include <cstdint>
#include <cstddef>

#define NG 3
#define NB 32
#define NT 1024
#define ND 512
#define NU 512

typedef __bf16 bf16x8 __attribute__((ext_vector_type(8)));
typedef float  f32x16 __attribute__((ext_vector_type(16)));

static __device__ __forceinline__ unsigned int f2bf(float f) {
    union { float f; unsigned int u; } v; v.f = f;
    return (v.u + 0x7FFFu + ((v.u >> 16) & 1u)) >> 16;   // RNE f32->bf16
}

// packed RNE f32x2 -> bf16x2 in one instruction
static __device__ __forceinline__ unsigned int cvt_pk_bf16(float lo, float hi) {
    unsigned int r;
    asm("v_cvt_pk_bf16_f32 %0, %1, %2" : "=v"(r) : "v"(lo), "v"(hi));
    return r;
}

static __device__ __forceinline__ bf16x8 ld_bf16x8(const char* base, int off) {
    return __builtin_bit_cast(bf16x8, *(const uint4*)(base + off));
}

#define AS1(p) ((const __attribute__((address_space(1))) void*)(p))
#define AS3(p) ((__attribute__((address_space(3))) void*)(p))

// ---------- kernel 1: qb[g,b,u] = sum_d query[g,b,d]*W1[g,d,u] + b1 + b2 ----------
__global__ __launch_bounds__(256) void prep_qb_kernel(
    const float* __restrict__ query, const float* __restrict__ W1,
    const float* __restrict__ b1, const float* __restrict__ b2,
    float* __restrict__ qb)
{
    __shared__ float qs[NB][ND];                    // 64 KiB
    const int g  = blockIdx.x >> 3;
    const int uc = blockIdx.x & 7;
    const int tid = threadIdx.x;

    const float4* qsrc = (const float4*)(query + (size_t)g * NB * ND);
    #pragma unroll
    for (int i = 0; i < 16; ++i)
        ((float4*)&qs[0][0])[tid + i * 256] = qsrc[tid + i * 256];
    __syncthreads();

    const int u  = uc * 64 + (tid & 63);
    const int b0 = tid >> 6;                        // 0..3
    float acc[8] = {};
    const float* w1col = W1 + (size_t)g * ND * NU + u;
    for (int d = 0; d < ND; ++d) {
        float w = w1col[(size_t)d * NU];            // coalesced over u
        #pragma unroll
        for (int j = 0; j < 8; ++j)
            acc[j] = fmaf(qs[b0 + 4 * j][d], w, acc[j]);  // LDS broadcast
    }
    const float bias = b1[g * NU + u] + b2[g * NU + u];
    #pragma unroll
    for (int j = 0; j < 8; ++j)
        qb[((size_t)g * NB + (b0 + 4 * j)) * NU + u] = acc[j] + bias;
}

// ---------- kernel 2: w2t = swizzled bf16 image of W2^T ----------
// Per g: 16 chunks (u-groups of 32) of 32 KiB. Within a chunk,
// byte(r,d) = r*1024 + ((d*2) ^ ((r&7)<<4)), r = u&31. Linear-DMA-ready.
__global__ __launch_bounds__(256) void prep_w2t_kernel(
    const float* __restrict__ W2, char* __restrict__ w2t)
{
    __shared__ float tile[64][65];                  // +1 pad: conflict-free transpose
    const int g  = blockIdx.x >> 6;
    const int tb = blockIdx.x & 63;
    const int d0 = (tb >> 3) * 64;
    const int u0 = (tb & 7) * 64;
    const int tx = threadIdx.x & 63;
    const int ty = threadIdx.x >> 6;

    const float* src = W2 + (size_t)g * ND * NU;
    #pragma unroll
    for (int k = 0; k < 16; ++k) {
        int r = ty + 4 * k;
        tile[r][tx] = src[(size_t)(d0 + r) * NU + (u0 + tx)];   // tile[d_loc][u_loc]
    }
    __syncthreads();
    char* dstg = w2t + (size_t)g * 16 * 32768;
    #pragma unroll
    for (int k = 0; k < 16; ++k) {
        int ul = ty + 4 * k;
        int u  = u0 + ul;
        int d  = d0 + tx;
        unsigned short h = (unsigned short)f2bf(tile[tx][ul]);
        int r = u & 31;
        size_t off = (size_t)(u >> 5) * 32768
                   + (size_t)(((r << 10) | (d << 1)) ^ ((r & 7) << 4));
        *(unsigned short*)(dstg + off) = h;
    }
}

// ---------- kernel 3: fused score = V . tanh(qb + values@W2) + bV ----------
// Ring-3 counted-vmcnt structure + HARD-FORCED A-panel register residency:
// every afrag passes through a volatile asm "+v" black-box before the loop.
// Volatile asm cannot be rematerialized, so the loads+cvt cannot be sunk
// into the uc-loop (the round-2..7 hidden ~3 GB L2 re-fetch).
__global__ __launch_bounds__(256, 2) void score_kernel(
    const float* __restrict__ values, const char* __restrict__ w2t,
    const float* __restrict__ qb, const float* __restrict__ Vvec,
    const float* __restrict__ bV, float* __restrict__ scores)
{
    __shared__ char  Bs[3][16384];                  // 48 KiB ring
    __shared__ float qbs[NU];
    __shared__ float Vs[NU];

    const int blk = blockIdx.x;
    const int g   = blk >> 8;                       // 256 blocks per g
    const int rem = blk & 255;
    const int b   = rem >> 3;
    const int t0  = (rem & 7) << 7;                 // 8 tiles of 128 rows
    const int tid  = threadIdx.x;
    const int lane = tid & 63;
    const int wave = tid >> 6;

    const char* w2g = w2t + ((size_t)g << 19);      // g * 512 KiB

    // stage half-chunk ph into buf: 16 KiB, 4 x 16B loads per thread
    auto stage = [&](int ph, char* buf) {
        const char* src = w2g + ((size_t)(ph >> 1) << 15) + ((ph & 1) << 9)
                        + (wave << 13) + ((lane >> 5) << 10) + ((lane & 31) << 4);
        char* dst = buf + (wave << 12) + (lane << 4);
        #pragma unroll
        for (int i = 0; i < 4; ++i)
            __builtin_amdgcn_global_load_lds(AS1(src + (i << 11)),
                                             AS3(dst + (i << 10)), 16, 0, 0);
    };

    {   // qb(+biases) and V via LDS-DMA
        const float* qsrc = qb + ((size_t)g * NB + b) * NU;
        const float* vsrc = Vvec + (size_t)g * NU;
        __builtin_amdgcn_global_load_lds(AS1(qsrc + tid),       AS3(&qbs[tid]),       4, 0, 0);
        __builtin_amdgcn_global_load_lds(AS1(qsrc + tid + 256), AS3(&qbs[tid + 256]), 4, 0, 0);
        __builtin_amdgcn_global_load_lds(AS1(vsrc + tid),       AS3(&Vs[tid]),        4, 0, 0);
        __builtin_amdgcn_global_load_lds(AS1(vsrc + tid + 256), AS3(&Vs[tid + 256]),  4, 0, 0);
    }
    stage(0, Bs[0]);
    stage(1, Bs[1]);

    // ---- A tile -> registers (bf16 MFMA fragments), static indices ----
    bf16x8 afrag[32];
    {
        const int arow_t = t0 + (wave << 5) + (lane & 31);
        const float* arow = values + (((size_t)g * NB + b) * NT + arow_t) * ND;
        const int acol = (lane >> 5) << 3;          // k-half of fragment: 0 or 8
        #pragma unroll
        for (int kk = 0; kk < 32; ++kk) {
            const float4* ap = (const float4*)(arow + (kk << 4) + acol);
            float4 v0 = ap[0], v1 = ap[1];
            union { bf16x8 v; unsigned int u[4]; } t;
            t.u[0] = cvt_pk_bf16(v0.x, v0.y);
            t.u[1] = cvt_pk_bf16(v0.z, v0.w);
            t.u[2] = cvt_pk_bf16(v1.x, v1.y);
            t.u[3] = cvt_pk_bf16(v1.z, v1.w);
            afrag[kk] = t.v;
        }
    }

    // ---- residency pins: volatile asm black-box, un-rematerializable.
    //      Every later use reads the asm OUTPUT register, so the whole
    //      A-panel must stay live in VGPRs across the main loop. ----
    #pragma unroll
    for (int kk = 0; kk < 32; ++kk)
        asm volatile("" : "+v"(afrag[kk]));

    asm volatile("s_waitcnt vmcnt(0) lgkmcnt(0)" ::: "memory");
    __builtin_amdgcn_s_barrier();

    const int brow  = lane & 31;
    const int bswz  = (brow & 7) << 4;
    const int bbase = (brow << 9) + ((lane >> 5) << 4);

    float p[16] = {};                               // per-lane score partials

    char* bA = (char*)Bs[0];                        // even-phase read buffer
    char* bB = (char*)Bs[1];                        // odd-phase read buffer
    char* bC = (char*)Bs[2];                        // even-phase stage target

    #pragma unroll 1
    for (int uc = 0; uc < 16; ++uc) {
        const int ph0 = uc << 1;
        f32x16 acc0 = (f32x16)(0.0f);
        f32x16 acc1 = (f32x16)(0.0f);

        // ===== even phase: reads bA (k 0..255), stages ph0+2 into bC =====
        if (uc < 15) stage(ph0 + 2, bC);
        __builtin_amdgcn_s_setprio(1);
        #pragma unroll
        for (int kk = 0; kk < 16; kk += 2) {
            bf16x8 b0 = ld_bf16x8(bA, (bbase + (kk << 5)) ^ bswz);
            bf16x8 b1 = ld_bf16x8(bA, (bbase + ((kk + 1) << 5)) ^ bswz);
            acc0 = __builtin_amdgcn_mfma_f32_32x32x16_bf16(afrag[kk],     b0, acc0, 0, 0, 0);
            acc1 = __builtin_amdgcn_mfma_f32_32x32x16_bf16(afrag[kk + 1], b1, acc1, 0, 0, 0);
        }
        __builtin_amdgcn_s_setprio(0);
        if (uc < 15) {
            asm volatile("s_waitcnt vmcnt(4)" ::: "memory");   // ph0+1 landed; ph0+2 in flight
        } else {
            asm volatile("s_waitcnt vmcnt(0)" ::: "memory");   // tail: ph 31 landed
        }
        __builtin_amdgcn_s_barrier();

        // ===== odd phase: reads bB (k 256..511), stages ph0+3 into old bA =====
        if (uc < 15) stage(ph0 + 3, bA);
        __builtin_amdgcn_s_setprio(1);
        #pragma unroll
        for (int kk = 0; kk < 16; kk += 2) {
            bf16x8 b0 = ld_bf16x8(bB, (bbase + (kk << 5)) ^ bswz);
            bf16x8 b1 = ld_bf16x8(bB, (bbase + ((kk + 1) << 5)) ^ bswz);
            acc0 = __builtin_amdgcn_mfma_f32_32x32x16_bf16(afrag[16 + kk],     b0, acc0, 0, 0, 0);
            acc1 = __builtin_amdgcn_mfma_f32_32x32x16_bf16(afrag[16 + kk + 1], b1, acc1, 0, 0, 0);
        }
        __builtin_amdgcn_s_setprio(0);

        // epilogue: tanh + V-dot for u-chunk uc
        {
            const int u = (uc << 5) + brow;
            const float qv = qbs[u], vv = Vs[u];
            #pragma unroll
            for (int r = 0; r < 16; ++r) {
                // tanh(x) = 1 - 2/(exp2(2*log2e*x)+1)
                float x  = (acc0[r] + acc1[r]) + qv;
                float e  = exp2f(2.8853900817779268f * x);
                float th = 1.0f - 2.0f * __builtin_amdgcn_rcpf(e + 1.0f);
                p[r] = fmaf(th, vv, p[r]);
            }
        }

        if (uc < 15) {
            asm volatile("s_waitcnt vmcnt(4)" ::: "memory");   // ph0+2 landed; ph0+3 in flight
            __builtin_amdgcn_s_barrier();
        }

        // rotate ring: (A,B,C) <- (C,A,B)
        char* t = bA; bA = bC; bC = bB; bB = t;
    }

    // reduce over u-columns (each 32-lane half sums its 32 cols)
    #pragma unroll
    for (int r = 0; r < 16; ++r) {
        float v = p[r];
        v += __shfl_xor(v, 1);
        v += __shfl_xor(v, 2);
        v += __shfl_xor(v, 4);
        v += __shfl_xor(v, 8);
        v += __shfl_xor(v, 16);
        p[r] = v;
    }
    if ((lane & 31) == 0) {
        const float bv = bV[g];
        float* srow = scores + ((size_t)g * NB + b) * NT + t0 + (wave << 5);
        #pragma unroll
        for (int r = 0; r < 16; ++r) {
            int t_local = (r & 3) + 8 * (r >> 2) + 4 * (lane >> 5);   // 32x32 C/D row map
            srow[t_local] = p[r] + bv;
        }
    }
}

// ---------- kernel 4: softmax over T + context, 4 d-slices per (g,b) ----------
__global__ __launch_bounds__(256) void finish_kernel(
    const float* __restrict__ scores, const float* __restrict__ values,
    float* __restrict__ out_ctx, float* __restrict__ out_w)
{
    __shared__ float sl[NT];
    __shared__ float red[16];
    __shared__ float cred[4][128];
    const int blk   = blockIdx.x;
    const int gb    = blk >> 2;                     // 0..95
    const int slice = blk & 3;                      // d-slice of 128
    const int tid = threadIdx.x;
    const int lane = tid & 63, wid = tid >> 6;

    const float* srow = scores + (size_t)gb * NT;
    float s[4];
    #pragma unroll
    for (int j = 0; j < 4; ++j) s[j] = srow[tid + 256 * j];

    float m = fmaxf(fmaxf(s[0], s[1]), fmaxf(s[2], s[3]));
    #pragma unroll
    for (int mask = 32; mask; mask >>= 1) m = fmaxf(m, __shfl_xor(m, mask));
    if (lane == 0) red[wid] = m;
    __syncthreads();
    const float gm = fmaxf(fmaxf(red[0], red[1]), fmaxf(red[2], red[3]));

    float e[4], ps = 0.f;
    #pragma unroll
    for (int j = 0; j < 4; ++j) { e[j] = __expf(s[j] - gm); ps += e[j]; }
    #pragma unroll
    for (int mask = 32; mask; mask >>= 1) ps += __shfl_xor(ps, mask);
    if (lane == 0) red[8 + wid] = ps;
    __syncthreads();
    const float inv = 1.f / (red[8] + red[9] + red[10] + red[11]);

    #pragma unroll
    for (int j = 0; j < 4; ++j) {
        float w = e[j] * inv;
        sl[tid + 256 * j] = w;
        if (slice == 0) out_w[(size_t)gb * NT + tid + 256 * j] = w;
    }
    __syncthreads();

    // context for this 128-d slice: 64 d-pairs x 4 t-interleaved groups
    const int dp = tid & 63;
    const int tg = tid >> 6;
    const float* vbase = values + (size_t)gb * NT * ND + slice * 128 + dp * 2;
    float ax = 0.f, ay = 0.f;
    #pragma unroll 4
    for (int t = tg; t < NT; t += 4) {
        float2 v = *(const float2*)(vbase + (size_t)t * ND);
        float w = sl[t];                            // broadcast within tg group
        ax = fmaf(w, v.x, ax);
        ay = fmaf(w, v.y, ay);
    }
    cred[tg][dp * 2]     = ax;
    cred[tg][dp * 2 + 1] = ay;
    __syncthreads();
    if (tid < 128) {
        float r = cred[0][tid] + cred[1][tid] + cred[2][tid] + cred[3][tid];
        out_ctx[(size_t)gb * ND + slice * 128 + tid] = r;
    }
}

extern "C" void kernel_launch(void* const* d_in, const int* in_sizes, int n_in,
                              void* d_out, int out_size, void* d_ws, size_t ws_size,
                              hipStream_t stream)
{
    (void)in_sizes; (void)n_in; (void)out_size; (void)ws_size;
    const float* query  = (const float*)d_in[0];
    const float* values = (const float*)d_in[1];
    const float* W1     = (const float*)d_in[2];
    const float* b1     = (const float*)d_in[3];
    const float* W2     = (const float*)d_in[4];
    const float* b2     = (const float*)d_in[5];
    const float* Vv     = (const float*)d_in[6];
    const float* bV     = (const float*)d_in[7];

    float* out_ctx = (float*)d_out;
    float* out_w   = out_ctx + (size_t)NG * NB * ND;

    // ws: qb (192 KiB) | scores (384 KiB) | w2t swizzled bf16 image (1.5 MiB)
    float* qb     = (float*)d_ws;
    float* scores = qb + (size_t)NG * NB * NU;
    char*  w2t    = (char*)(scores + (size_t)NG * NB * NT);

    prep_qb_kernel <<<NG * 8,             256, 0, stream>>>(query, W1, b1, b2, qb);
    prep_w2t_kernel<<<NG * 64,            256, 0, stream>>>(W2, w2t);
    score_kernel   <<<NG * NB * (NT/128), 256, 0, stream>>>(values, w2t, qb, Vv, bV, scores);
    finish_kernel  <<<NG * NB * 4,        256, 0, stream>>>(scores, values, out_ctx, out_w);
}